// Round 1
// baseline (716.534 us; speedup 1.0000x reference)
//
#include <hip/hip_runtime.h>
#include <hip/hip_bf16.h>

// MOELoraLinear: out[b,s,o] = x@W_base^T + b_base + SCALING * (softmax(router(mean_s x)) weighted LoRA)
// Strategy: fold LoRA-up into the base GEMM by extending K: Xext[8192,4160] = [bf16(x) | hw'],
// Wext[4096,4160] = [bf16(W_base) | lora_B], single bf16 MFMA GEMM K=4160 + bias epilogue.

typedef unsigned short u16;
typedef __attribute__((ext_vector_type(8))) short short8;       // 8 bf16 = 4 VGPRs (MFMA A/B frag)
typedef __attribute__((ext_vector_type(8))) unsigned short u16x8;
typedef __attribute__((ext_vector_type(4))) float f32x4;        // MFMA C/D frag

#define AS1(p) ((const __attribute__((address_space(1))) void*)(p))
#define AS3(p) ((__attribute__((address_space(3))) void*)(p))

constexpr int KM   = 4160;   // extended K = 4096 + 64, also row stride of Xext/Wext
constexpr int NOUT = 4096;   // O
constexpr int MTOT = 8192;   // B*S

__device__ __forceinline__ u16 f2bf(float f) {
    union { float f; unsigned int u; } v; v.f = f;
    unsigned int r = v.u + 0x7fffu + ((v.u >> 16) & 1u);   // RNE
    return (u16)(r >> 16);
}

// ---- convert fp32 [rows][4096] -> bf16 into [rows][4160] (cols 0..4095), 8 elems/thread ----
__global__ void k_conv8(const float* __restrict__ src, u16* __restrict__ dst) {
    size_t t = (size_t)blockIdx.x * 256 + threadIdx.x;
    size_t base = t * 8;
    size_t row = base >> 12;          // /4096
    int col = (int)(base & 4095);
    const float4* s = (const float4*)(src + base);
    float4 v0 = s[0], v1 = s[1];
    u16x8 o;
    o[0] = f2bf(v0.x); o[1] = f2bf(v0.y); o[2] = f2bf(v0.z); o[3] = f2bf(v0.w);
    o[4] = f2bf(v1.x); o[5] = f2bf(v1.y); o[6] = f2bf(v1.z); o[7] = f2bf(v1.w);
    *(u16x8*)(dst + row * KM + col) = o;
}

// ---- lora_B [E,O,R] fp32 -> Wext[o][4096 + e*8 + r] bf16 ----
__global__ void k_wlora(const float* __restrict__ lb, u16* __restrict__ Wext) {
    int f = blockIdx.x * 256 + threadIdx.x;      // f = (e*4096 + o)*8 + r
    int e = f >> 15;
    int o = (f >> 3) & 4095;
    int r = f & 7;
    Wext[(size_t)o * KM + 4096 + e * 8 + r] = f2bf(lb[f]);
}

// ---- lora_A [E,R,D] fp32 -> Abf [64][4096] bf16 (same flat layout) ----
__global__ void k_abf(const float* __restrict__ la, u16* __restrict__ Abf) {
    int f = blockIdx.x * 256 + threadIdx.x;
    Abf[f] = f2bf(la[f]);
}

// ---- router partial: logits_raw[b,e] += sum_{s in chunk, d in chunk} x[b,s,d]*rW[e,d] ----
__global__ void k_router(const float* __restrict__ x, const float* __restrict__ rW,
                         float* __restrict__ logits_raw) {
    int b = blockIdx.x >> 8;               // 4 batches
    int rem = blockIdx.x & 255;
    int dchunk = rem >> 4, schunk = rem & 15;
    int t = threadIdx.x;
    int d = dchunk * 256 + t;
    const float* xp = x + ((size_t)(b * 2048 + schunk * 128)) * 4096 + d;
    float xs = 0.f;
    #pragma unroll 4
    for (int s = 0; s < 128; s++) xs += xp[(size_t)s * 4096];
    __shared__ float red[256];
    for (int e = 0; e < 8; e++) {
        red[t] = xs * rW[e * 4096 + d];
        __syncthreads();
        for (int off = 128; off > 0; off >>= 1) {
            if (t < off) red[t] += red[t + off];
            __syncthreads();
        }
        if (t == 0) atomicAdd(&logits_raw[b * 8 + e], red[0]);
        __syncthreads();
    }
}

// ---- softmax: wsc[b,e] = SCALING * softmax(logits_raw/S + rb) ----
__global__ void k_softmax(const float* __restrict__ logits_raw, const float* __restrict__ rb,
                          float* __restrict__ wsc) {
    int b = threadIdx.x;
    if (b >= 4) return;
    float l[8], mx = -1e30f;
    for (int e = 0; e < 8; e++) { l[e] = logits_raw[b * 8 + e] / 2048.0f + rb[e]; mx = fmaxf(mx, l[e]); }
    float s = 0.f;
    for (int e = 0; e < 8; e++) { l[e] = expf(l[e] - mx); s += l[e]; }
    for (int e = 0; e < 8; e++) wsc[b * 8 + e] = 2.0f * l[e] / s;   // SCALING = 2.0
}

// ---- h-GEMM: hw'[m, er] = (Xbf[m,:4096] @ Abf[er,:]) * wsc[b(m), e] -> bf16 into Xext cols 4096+ ----
// 1 wave/block, 64x64 tile, 4x4 of 16x16x32 MFMA, K=4096
__global__ __launch_bounds__(64) void k_hgemm(const u16* __restrict__ Xb, const u16* __restrict__ Ab,
                                              const float* __restrict__ wsc, u16* __restrict__ Hout) {
    __shared__ u16 As[64 * 32];
    __shared__ u16 Bs[64 * 32];
    const int lane = threadIdx.x;
    const int m0 = blockIdx.x * 64;
    f32x4 acc[4][4] = {};
    const int aoff = (lane & 15) * 32 + (lane >> 4) * 8;

    for (int kt = 0; kt < 4096; kt += 32) {
        #pragma unroll
        for (int i = 0; i < 4; i++) {
            int f = lane + i * 64;
            int row = f >> 2, kk = (f & 3) * 8;
            __builtin_amdgcn_global_load_lds(AS1(Xb + (size_t)(m0 + row) * KM + kt + kk),
                                             AS3(As + f * 8), 16, 0, 0);
            __builtin_amdgcn_global_load_lds(AS1(Ab + (size_t)row * 4096 + kt + kk),
                                             AS3(Bs + f * 8), 16, 0, 0);
        }
        __builtin_amdgcn_s_waitcnt(0);   // single-wave block: force DMA drain
        __syncthreads();
        short8 af[4], bf[4];
        #pragma unroll
        for (int i = 0; i < 4; i++) af[i] = *(const short8*)(As + aoff + i * 16 * 32);
        #pragma unroll
        for (int j = 0; j < 4; j++) bf[j] = *(const short8*)(Bs + aoff + j * 16 * 32);
        #pragma unroll
        for (int i = 0; i < 4; i++)
            #pragma unroll
            for (int j = 0; j < 4; j++)
                acc[i][j] = __builtin_amdgcn_mfma_f32_16x16x32_bf16(af[i], bf[j], acc[i][j], 0, 0, 0);
        __syncthreads();
    }
    const int lrow = (lane >> 4) * 4, lcol = lane & 15;
    #pragma unroll
    for (int j = 0; j < 4; j++) {
        int er = j * 16 + lcol;
        int e = er >> 3;
        #pragma unroll
        for (int i = 0; i < 4; i++) {
            int row = m0 + i * 16 + lrow;
            float w = wsc[(row >> 11) * 8 + e];
            #pragma unroll
            for (int r = 0; r < 4; r++)
                Hout[(size_t)(row + r) * KM + 4096 + er] = f2bf(acc[i][j][r] * w);
        }
    }
}

// ---- main GEMM: C[8192,4096] = Xext[8192,4160] @ Wext[4096,4160]^T + bias ----
// m97 structure: 128x128 tile, 256 thr = 4 waves (2x2 quadrants of 64x64), BK=32,
// global_load_lds width-16 staging, 2-barrier K-loop.
__global__ __launch_bounds__(256) void k_main(const u16* __restrict__ A, const u16* __restrict__ B,
                                              const float* __restrict__ bias, float* __restrict__ C) {
    __shared__ u16 As[128 * 32];
    __shared__ u16 Bs[128 * 32];
    const int tid = threadIdx.x;
    const int lane = tid & 63;
    const int wave = tid >> 6;
    const int wm = (wave >> 1) * 64;
    const int wn = (wave & 1) * 64;
    const int m0 = blockIdx.y * 128;
    const int n0 = blockIdx.x * 128;

    f32x4 acc[4][4] = {};

    // staging: 16B chunk f covers LDS row f>>2, k-offset (f&3)*8; 2 issues of 256 chunks
    const int arow0 = tid >> 2, ak = (tid & 3) * 8;
    const int arow1 = (tid + 256) >> 2;
    const u16* Ag0 = A + (size_t)(m0 + arow0) * KM + ak;
    const u16* Ag1 = A + (size_t)(m0 + arow1) * KM + ak;
    const u16* Bg0 = B + (size_t)(n0 + arow0) * KM + ak;
    const u16* Bg1 = B + (size_t)(n0 + arow1) * KM + ak;
    u16* Asp0 = As + tid * 8;
    u16* Asp1 = As + (tid + 256) * 8;
    u16* Bsp0 = Bs + tid * 8;
    u16* Bsp1 = Bs + (tid + 256) * 8;

    const int aoff = (wm + (lane & 15)) * 32 + (lane >> 4) * 8;
    const int boff = (wn + (lane & 15)) * 32 + (lane >> 4) * 8;

    for (int kt = 0; kt < KM; kt += 32) {
        __builtin_amdgcn_global_load_lds(AS1(Ag0 + kt), AS3(Asp0), 16, 0, 0);
        __builtin_amdgcn_global_load_lds(AS1(Ag1 + kt), AS3(Asp1), 16, 0, 0);
        __builtin_amdgcn_global_load_lds(AS1(Bg0 + kt), AS3(Bsp0), 16, 0, 0);
        __builtin_amdgcn_global_load_lds(AS1(Bg1 + kt), AS3(Bsp1), 16, 0, 0);
        __syncthreads();
        short8 af[4], bf[4];
        #pragma unroll
        for (int i = 0; i < 4; i++) af[i] = *(const short8*)(As + aoff + i * 16 * 32);
        #pragma unroll
        for (int j = 0; j < 4; j++) bf[j] = *(const short8*)(Bs + boff + j * 16 * 32);
        #pragma unroll
        for (int i = 0; i < 4; i++)
            #pragma unroll
            for (int j = 0; j < 4; j++)
                acc[i][j] = __builtin_amdgcn_mfma_f32_16x16x32_bf16(af[i], bf[j], acc[i][j], 0, 0, 0);
        __syncthreads();
    }

    const int lrow = (lane >> 4) * 4, lcol = lane & 15;
    #pragma unroll
    for (int j = 0; j < 4; j++) {
        int col = n0 + wn + j * 16 + lcol;
        float bv = bias[col];
        #pragma unroll
        for (int i = 0; i < 4; i++) {
            int row = m0 + wm + i * 16 + lrow;
            float* Cp = C + (size_t)row * NOUT + col;
            #pragma unroll
            for (int r = 0; r < 4; r++)
                Cp[(size_t)r * NOUT] = acc[i][j][r] + bv;
        }
    }
}

extern "C" void kernel_launch(void* const* d_in, const int* in_sizes, int n_in,
                              void* d_out, int out_size, void* d_ws, size_t ws_size,
                              hipStream_t stream) {
    const float* x  = (const float*)d_in[0];   // [4,2048,4096]
    const float* Wb = (const float*)d_in[1];   // [4096,4096]
    const float* bb = (const float*)d_in[2];   // [4096]
    const float* lA = (const float*)d_in[3];   // [8,8,4096]
    const float* lB = (const float*)d_in[4];   // [8,4096,8]
    const float* rW = (const float*)d_in[5];   // [8,4096]
    const float* rb = (const float*)d_in[6];   // [8]
    float* out = (float*)d_out;                // [4,2048,4096] fp32

    char* ws = (char*)d_ws;
    float* logits = (float*)ws;                          // 32 fp32
    float* wsc    = (float*)(ws + 128);                  // 32 fp32
    u16* Abf      = (u16*)(ws + 256);                    // 64*4096 bf16 = 512 KiB
    u16* Xext     = (u16*)(ws + (1 << 20));              // 8192*4160 bf16 = 68.1 MB
    u16* Wext     = (u16*)(ws + (1 << 20) + 68157440ULL);// 4096*4160 bf16 = 34.1 MB

    hipMemsetAsync(logits, 0, 128, stream);

    k_conv8 <<<8192,  256, 0, stream>>>(Wb, Wext);          // W_base -> Wext[:, :4096]
    k_wlora <<<1024,  256, 0, stream>>>(lB, Wext);          // lora_B -> Wext[:, 4096:]
    k_abf   <<<1024,  256, 0, stream>>>(lA, Abf);           // lora_A -> bf16
    k_conv8 <<<16384, 256, 0, stream>>>(x, Xext);           // x -> Xext[:, :4096]
    k_router<<<1024,  256, 0, stream>>>(x, rW, logits);     // partial logits
    k_softmax<<<1, 64, 0, stream>>>(logits, rb, wsc);       // router weights * SCALING
    k_hgemm <<<128, 64, 0, stream>>>(Xext, Abf, wsc, Xext); // hw' -> Xext[:, 4096:]
    k_main  <<<dim3(32, 64), 256, 0, stream>>>(Xext, Wext, bb, out);
}

// Round 2
// 638.976 us; speedup vs baseline: 1.1214x; 1.1214x over previous
//
#include <hip/hip_runtime.h>
#include <hip/hip_bf16.h>

// MOELoraLinear: out = x@W_base^T + b_base + SCALING * router-weighted LoRA.
// LoRA-up folded into main GEMM via K-extension: Xext[8192,4160]=[bf16(x)|hw'],
// Wext[4096,4160]=[bf16(W_base)|lora_B]; one bf16 MFMA GEMM K=4160 + bias.
// R2: fused x-conv+colsum pass, no-atomic router, 4-wave K-split double-buffered h-GEMM.

typedef unsigned short u16;
typedef __attribute__((ext_vector_type(8))) short short8;       // 8 bf16 (MFMA A/B frag)
typedef __attribute__((ext_vector_type(8))) unsigned short u16x8;
typedef __attribute__((ext_vector_type(4))) float f32x4;        // MFMA C/D frag

#define AS1(p) ((const __attribute__((address_space(1))) void*)(p))
#define AS3(p) ((__attribute__((address_space(3))) void*)(p))

constexpr int KM   = 4160;   // extended K, row stride of Xext/Wext
constexpr int NOUT = 4096;

__device__ __forceinline__ u16 f2bf(float f) {
    union { float f; unsigned int u; } v; v.f = f;
    unsigned int r = v.u + 0x7fffu + ((v.u >> 16) & 1u);   // RNE
    return (u16)(r >> 16);
}

// ---- fused: x fp32 -> bf16 into Xext[:, :4096]  +  per-block column sums ----
// grid 512: b = blk>>7, sc = blk&127 -> rows [b*2048 + sc*16, +16)
__global__ __launch_bounds__(256) void k_convx(const float* __restrict__ x,
                                               u16* __restrict__ Xext,
                                               float* __restrict__ colpart) {
    const int t = threadIdx.x;
    const int row0 = (blockIdx.x >> 7) * 2048 + (blockIdx.x & 127) * 16;
    float4 cs[4] = {{0,0,0,0},{0,0,0,0},{0,0,0,0},{0,0,0,0}};   // [g*2+h]
    for (int r = 0; r < 16; ++r) {
        size_t roff = (size_t)(row0 + r) * 4096;
        #pragma unroll
        for (int g = 0; g < 2; ++g) {
            int col = g * 2048 + t * 8;
            const float4* p = (const float4*)(x + roff + col);
            float4 v0 = p[0], v1 = p[1];
            cs[2*g].x += v0.x; cs[2*g].y += v0.y; cs[2*g].z += v0.z; cs[2*g].w += v0.w;
            cs[2*g+1].x += v1.x; cs[2*g+1].y += v1.y; cs[2*g+1].z += v1.z; cs[2*g+1].w += v1.w;
            u16x8 o;
            o[0]=f2bf(v0.x); o[1]=f2bf(v0.y); o[2]=f2bf(v0.z); o[3]=f2bf(v0.w);
            o[4]=f2bf(v1.x); o[5]=f2bf(v1.y); o[6]=f2bf(v1.z); o[7]=f2bf(v1.w);
            *(u16x8*)(Xext + (size_t)(row0 + r) * KM + col) = o;
        }
    }
    float* cp = colpart + (size_t)blockIdx.x * 4096;
    #pragma unroll
    for (int g = 0; g < 2; ++g) {
        *(float4*)(cp + g * 2048 + t * 8)     = cs[2*g];
        *(float4*)(cp + g * 2048 + t * 8 + 4) = cs[2*g+1];
    }
}

// ---- logits_raw[b,e] = sum_col colsum[b,col] * rW[e,col]  (grid 32 = b*8+e) ----
__global__ __launch_bounds__(256) void k_logit(const float* __restrict__ colpart,
                                               const float* __restrict__ rW,
                                               float* __restrict__ logits) {
    const int b = blockIdx.x >> 3, e = blockIdx.x & 7;
    const int t = threadIdx.x;
    const int c0 = t * 16;
    float4 rw[4];
    #pragma unroll
    for (int j = 0; j < 4; ++j) rw[j] = *(const float4*)(rW + e * 4096 + c0 + j * 4);
    float acc = 0.f;
    for (int sc = 0; sc < 128; ++sc) {
        const float4* p = (const float4*)(colpart + ((size_t)(b * 128 + sc)) * 4096 + c0);
        #pragma unroll
        for (int j = 0; j < 4; ++j) {
            float4 v = p[j];
            acc += v.x * rw[j].x + v.y * rw[j].y + v.z * rw[j].z + v.w * rw[j].w;
        }
    }
    __shared__ float red[256];
    red[t] = acc;
    __syncthreads();
    for (int off = 128; off > 0; off >>= 1) {
        if (t < off) red[t] += red[t + off];
        __syncthreads();
    }
    if (t == 0) logits[b * 8 + e] = red[0];
}

// ---- W_base fp32 [4096][4096] -> bf16 into Wext[:, :4096] ----
__global__ void k_conv8(const float* __restrict__ src, u16* __restrict__ dst) {
    size_t t = (size_t)blockIdx.x * 256 + threadIdx.x;
    size_t base = t * 8;
    size_t row = base >> 12;
    int col = (int)(base & 4095);
    const float4* s = (const float4*)(src + base);
    float4 v0 = s[0], v1 = s[1];
    u16x8 o;
    o[0]=f2bf(v0.x); o[1]=f2bf(v0.y); o[2]=f2bf(v0.z); o[3]=f2bf(v0.w);
    o[4]=f2bf(v1.x); o[5]=f2bf(v1.y); o[6]=f2bf(v1.z); o[7]=f2bf(v1.w);
    *(u16x8*)(dst + row * KM + col) = o;
}

// ---- lora_B [E,O,R] fp32 -> Wext[o][4096 + e*8 + r] ----
__global__ void k_wlora(const float* __restrict__ lb, u16* __restrict__ Wext) {
    int f = blockIdx.x * 256 + threadIdx.x;
    int e = f >> 15, o = (f >> 3) & 4095, r = f & 7;
    Wext[(size_t)o * KM + 4096 + e * 8 + r] = f2bf(lb[f]);
}

// ---- lora_A [E,R,D] fp32 -> Abf [64][4096] bf16 ----
__global__ void k_abf(const float* __restrict__ la, u16* __restrict__ Abf) {
    int f = blockIdx.x * 256 + threadIdx.x;
    Abf[f] = f2bf(la[f]);
}

// ---- h-GEMM: Xext[:, 4096+er] = f2bf( (Xbf @ Abf^T)[m,er] * SCALING*softmax(...)[b(m),e] )
// grid 256 blocks x 256 thr (4 waves). M-tile 32. Each wave owns K-chunk of 1024,
// private double-buffered LDS, no in-loop barriers; cross-wave LDS reduce at end.
__global__ __launch_bounds__(256) void k_hgemm(const u16* __restrict__ Xb,
                                               const u16* __restrict__ Ab,
                                               const float* __restrict__ logits,
                                               const float* __restrict__ rb,
                                               u16* __restrict__ Hout) {
    __shared__ u16 As[8 * 1024];     // [wave*2+buf][32*32]
    __shared__ u16 Bs[8 * 2048];     // [wave*2+buf][64*32]
    __shared__ float Red[4 * 2048];  // [wave][32*64]
    __shared__ float wscL[8];
    const int tid = threadIdx.x, lane = tid & 63, w = tid >> 6;
    const int m0 = blockIdx.x * 32;
    const int b = blockIdx.x >> 6;      // batch (2048 rows = 64 blocks per batch)

    if (tid < 8) {
        float l[8], mx = -1e30f;
        #pragma unroll
        for (int j = 0; j < 8; ++j) {
            l[j] = logits[b * 8 + j] * (1.0f / 2048.0f) + rb[j];
            mx = fmaxf(mx, l[j]);
        }
        float s = 0.f;
        #pragma unroll
        for (int j = 0; j < 8; ++j) s += expf(l[j] - mx);
        wscL[tid] = 2.0f * expf(l[tid] - mx) / s;   // SCALING = 2.0
    }
    // drain the logits/rb loads so they don't pollute vmcnt bookkeeping below
    asm volatile("s_waitcnt vmcnt(0)" ::: "memory");

    f32x4 acc[2][4] = {};
    const int kbase = w * 1024;

    auto issue = [&](int it, int buf) {
        const int kt = kbase + it * 32;
        u16* Aw = As + (w * 2 + buf) * 1024;
        u16* Bw = Bs + (w * 2 + buf) * 2048;
        #pragma unroll
        for (int i = 0; i < 2; ++i) {
            int f = lane + i * 64;
            __builtin_amdgcn_global_load_lds(
                AS1(Xb + (size_t)(m0 + (f >> 2)) * KM + kt + (f & 3) * 8),
                AS3(Aw + f * 8), 16, 0, 0);
        }
        #pragma unroll
        for (int i = 0; i < 4; ++i) {
            int f = lane + i * 64;
            __builtin_amdgcn_global_load_lds(
                AS1(Ab + (size_t)(f >> 2) * 4096 + kt + (f & 3) * 8),
                AS3(Bw + f * 8), 16, 0, 0);
        }
    };

    issue(0, 0);
    for (int it = 0; it < 32; ++it) {
        const int buf = it & 1;
        if (it + 1 < 32) {
            issue(it + 1, buf ^ 1);
            asm volatile("s_waitcnt vmcnt(6)" ::: "memory");   // drain the 6 older (this iter's) DMAs
        } else {
            asm volatile("s_waitcnt vmcnt(0)" ::: "memory");
        }
        const u16* Aw = As + (w * 2 + buf) * 1024;
        const u16* Bw = Bs + (w * 2 + buf) * 2048;
        short8 af[2], bfr[4];
        #pragma unroll
        for (int mi = 0; mi < 2; ++mi)
            af[mi] = *(const short8*)(Aw + (mi * 16 + (lane & 15)) * 32 + (lane >> 4) * 8);
        #pragma unroll
        for (int nj = 0; nj < 4; ++nj)
            bfr[nj] = *(const short8*)(Bw + (nj * 16 + (lane & 15)) * 32 + (lane >> 4) * 8);
        #pragma unroll
        for (int mi = 0; mi < 2; ++mi)
            #pragma unroll
            for (int nj = 0; nj < 4; ++nj)
                acc[mi][nj] = __builtin_amdgcn_mfma_f32_16x16x32_bf16(af[mi], bfr[nj], acc[mi][nj], 0, 0, 0);
        asm volatile("" ::: "memory");
    }

    const int quad = lane >> 4, lcol = lane & 15;
    #pragma unroll
    for (int mi = 0; mi < 2; ++mi)
        #pragma unroll
        for (int nj = 0; nj < 4; ++nj)
            #pragma unroll
            for (int r = 0; r < 4; ++r)
                Red[w * 2048 + (mi * 16 + quad * 4 + r) * 64 + nj * 16 + lcol] = acc[mi][nj][r];
    __syncthreads();

    const int o = tid * 8, row = o >> 6, col = o & 63;
    float s0=0,s1=0,s2=0,s3=0,s4=0,s5=0,s6=0,s7=0;
    #pragma unroll
    for (int ww = 0; ww < 4; ++ww) {
        const float4* p = (const float4*)(Red + ww * 2048 + o);
        float4 v0 = p[0], v1 = p[1];
        s0+=v0.x; s1+=v0.y; s2+=v0.z; s3+=v0.w;
        s4+=v1.x; s5+=v1.y; s6+=v1.z; s7+=v1.w;
    }
    const float wgt = wscL[col >> 3];
    u16x8 out;
    out[0]=f2bf(s0*wgt); out[1]=f2bf(s1*wgt); out[2]=f2bf(s2*wgt); out[3]=f2bf(s3*wgt);
    out[4]=f2bf(s4*wgt); out[5]=f2bf(s5*wgt); out[6]=f2bf(s6*wgt); out[7]=f2bf(s7*wgt);
    *(u16x8*)(Hout + (size_t)(m0 + row) * KM + 4096 + col) = out;
}

// ---- main GEMM: C[8192,4096] = Xext @ Wext^T + bias (m97 structure, unchanged) ----
__global__ __launch_bounds__(256) void k_main(const u16* __restrict__ A, const u16* __restrict__ B,
                                              const float* __restrict__ bias, float* __restrict__ C) {
    __shared__ u16 As[128 * 32];
    __shared__ u16 Bs[128 * 32];
    const int tid = threadIdx.x;
    const int lane = tid & 63;
    const int wave = tid >> 6;
    const int wm = (wave >> 1) * 64;
    const int wn = (wave & 1) * 64;
    const int m0 = blockIdx.y * 128;
    const int n0 = blockIdx.x * 128;

    f32x4 acc[4][4] = {};

    const int arow0 = tid >> 2, ak = (tid & 3) * 8;
    const int arow1 = (tid + 256) >> 2;
    const u16* Ag0 = A + (size_t)(m0 + arow0) * KM + ak;
    const u16* Ag1 = A + (size_t)(m0 + arow1) * KM + ak;
    const u16* Bg0 = B + (size_t)(n0 + arow0) * KM + ak;
    const u16* Bg1 = B + (size_t)(n0 + arow1) * KM + ak;
    u16* Asp0 = As + tid * 8;
    u16* Asp1 = As + (tid + 256) * 8;
    u16* Bsp0 = Bs + tid * 8;
    u16* Bsp1 = Bs + (tid + 256) * 8;

    const int aoff = (wm + (lane & 15)) * 32 + (lane >> 4) * 8;
    const int boff = (wn + (lane & 15)) * 32 + (lane >> 4) * 8;

    for (int kt = 0; kt < KM; kt += 32) {
        __builtin_amdgcn_global_load_lds(AS1(Ag0 + kt), AS3(Asp0), 16, 0, 0);
        __builtin_amdgcn_global_load_lds(AS1(Ag1 + kt), AS3(Asp1), 16, 0, 0);
        __builtin_amdgcn_global_load_lds(AS1(Bg0 + kt), AS3(Bsp0), 16, 0, 0);
        __builtin_amdgcn_global_load_lds(AS1(Bg1 + kt), AS3(Bsp1), 16, 0, 0);
        __syncthreads();
        short8 af[4], bf[4];
        #pragma unroll
        for (int i = 0; i < 4; i++) af[i] = *(const short8*)(As + aoff + i * 16 * 32);
        #pragma unroll
        for (int j = 0; j < 4; j++) bf[j] = *(const short8*)(Bs + boff + j * 16 * 32);
        #pragma unroll
        for (int i = 0; i < 4; i++)
            #pragma unroll
            for (int j = 0; j < 4; j++)
                acc[i][j] = __builtin_amdgcn_mfma_f32_16x16x32_bf16(af[i], bf[j], acc[i][j], 0, 0, 0);
        __syncthreads();
    }

    const int lrow = (lane >> 4) * 4, lcol = lane & 15;
    #pragma unroll
    for (int j = 0; j < 4; j++) {
        int col = n0 + wn + j * 16 + lcol;
        float bv = bias[col];
        #pragma unroll
        for (int i = 0; i < 4; i++) {
            int row = m0 + wm + i * 16 + lrow;
            float* Cp = C + (size_t)row * NOUT + col;
            #pragma unroll
            for (int r = 0; r < 4; r++)
                Cp[(size_t)r * NOUT] = acc[i][j][r] + bv;
        }
    }
}

extern "C" void kernel_launch(void* const* d_in, const int* in_sizes, int n_in,
                              void* d_out, int out_size, void* d_ws, size_t ws_size,
                              hipStream_t stream) {
    const float* x  = (const float*)d_in[0];   // [4,2048,4096]
    const float* Wb = (const float*)d_in[1];   // [4096,4096]
    const float* bb = (const float*)d_in[2];   // [4096]
    const float* lA = (const float*)d_in[3];   // [8,8,4096]
    const float* lB = (const float*)d_in[4];   // [8,4096,8]
    const float* rW = (const float*)d_in[5];   // [8,4096]
    const float* rb = (const float*)d_in[6];   // [8]
    float* out = (float*)d_out;                // [4,2048,4096] fp32

    char* ws = (char*)d_ws;
    float* logits = (float*)ws;                           // 32 fp32
    u16* Abf      = (u16*)(ws + 256);                     // 64*4096 bf16 = 512 KiB
    u16* Xext     = (u16*)(ws + (1 << 20));               // 8192*4160 bf16 = 68.1 MB
    u16* Wext     = (u16*)(ws + (1 << 20) + 68157440ULL); // 4096*4160 bf16 = 34.1 MB
    // colpart [512][4096] fp32 = 8 MB, overlaid on Wext region: it is fully
    // consumed by k_logit BEFORE k_conv8/k_wlora write Wext (stream-ordered).
    float* colpart = (float*)Wext;

    k_abf   <<<1024, 256, 0, stream>>>(lA, Abf);             // lora_A -> bf16
    k_convx <<<512,  256, 0, stream>>>(x, Xext, colpart);    // x -> bf16 + column sums
    k_logit <<<32,   256, 0, stream>>>(colpart, rW, logits); // raw router logits
    k_hgemm <<<256,  256, 0, stream>>>(Xext, Abf, logits, rb, Xext); // hw' -> Xext[:,4096:]
    k_conv8 <<<8192, 256, 0, stream>>>(Wb, Wext);            // W_base -> Wext[:, :4096]
    k_wlora <<<1024, 256, 0, stream>>>(lB, Wext);            // lora_B -> Wext[:, 4096:]
    k_main  <<<dim3(32, 64), 256, 0, stream>>>(Xext, Wext, bb, out);
}